// Round 2
// baseline (119.427 us; speedup 1.0000x reference)
//
#include <hip/hip_runtime.h>

#define ROWS 1024
#define PTS 6144              // points per batch row (2048*3)
#define NDIH (PTS - 3)        // 6141 dihedrals per row
#define ROWF (PTS * 3)        // 18432 floats per row
#define ROWF4 (ROWF / 4)      // 4608 float4 per row
#define CHUNK 1024            // dihedrals per block
#define DPT 4                 // dihedrals per thread
#define THREADS 256           // CHUNK / DPT
#define NCHUNK 6              // ceil(6141/1024)
#define ANG_PER_ROW (2 * NDIH)                // 12282
#define SFLOATS ((CHUNK + 3) * 3 + 3)         // 3084 floats = 12.3 KB
#define EPS_SHIFT 1e-8f

typedef float v2 __attribute__((ext_vector_type(2)));

static __device__ __forceinline__ v2 mk2(float a, float b) {
    v2 r; r[0] = a; r[1] = b; return r;
}

__global__ __launch_bounds__(THREADS) void dih_kernel(const float* __restrict__ in,
                                                      float* __restrict__ out) {
    __shared__ float s[SFLOATS];
    const int b     = blockIdx.x / NCHUNK;
    const int chunk = blockIdx.x % NCHUNK;
    const int i0    = chunk * CHUNK;
    const int t     = threadIdx.x;
    const int wid   = t >> 6;
    const int lane  = t & 63;

    // ---- per-wave async global -> LDS staging (no VGPR round trip, no barrier) ----
    const float4* g4  = (const float4*)(in + (size_t)b * ROWF);
    const int cbase   = chunk * (CHUNK * 3 / 4);     // 768 * chunk, f4 index of chunk start
    #pragma unroll
    for (int p = 0; p < 4; ++p) {
        const int rel = p * 64 + lane;               // 0..255 within wave's slice
        const int f4i = 192 * wid + rel;             // LDS f4 destination index
        if (rel < 195 && (cbase + f4i) < ROWF4) {
            __builtin_amdgcn_global_load_lds(
                (const __attribute__((address_space(1))) void*)(g4 + cbase + f4i),
                (__attribute__((address_space(3))) void*)(s + (192 * wid + p * 64) * 4),
                16, 0, 0);
        }
    }
    // wait only for THIS wave's loads; each wave reads only what it wrote
    asm volatile("s_waitcnt vmcnt(0)" ::: "memory");
    __builtin_amdgcn_sched_barrier(0);

    // first_three output (x[:, :3, :]) — once per row, from chunk 0
    if (chunk == 0 && t < 9)
        out[(size_t)ROWS * ANG_PER_ROW + (size_t)b * 9 + t] = s[t];

    // ---- 21-float window (points i0+4t .. i0+4t+6) via 5x ds_read_b128 + 1 ----
    float w[21];
    {
        const float4* ls4 = (const float4*)(s + 12 * t);
        float4 v0 = ls4[0], v1 = ls4[1], v2v = ls4[2], v3 = ls4[3], v4 = ls4[4];
        w[0]=v0.x;  w[1]=v0.y;  w[2]=v0.z;  w[3]=v0.w;
        w[4]=v1.x;  w[5]=v1.y;  w[6]=v1.z;  w[7]=v1.w;
        w[8]=v2v.x; w[9]=v2v.y; w[10]=v2v.z; w[11]=v2v.w;
        w[12]=v3.x; w[13]=v3.y; w[14]=v3.z; w[15]=v3.w;
        w[16]=v4.x; w[17]=v4.y; w[18]=v4.z; w[19]=v4.w;
        w[20]=s[12 * t + 20];
    }

    // ---- shared edge differences e_j = x_j - x_{j+1}, j = 0..5 ----
    float ex[6], ey[6], ez[6];
    #pragma unroll
    for (int j = 0; j < 6; ++j) {
        ex[j] = w[3*j + 0] - w[3*j + 3];
        ey[j] = w[3*j + 1] - w[3*j + 4];
        ez[j] = w[3*j + 2] - w[3*j + 5];
    }

    // ---- packed-f32 core: process dihedral pairs (p, p+1) in v2 registers ----
    // Targets v_pk_fma_f32 / v_pk_mul_f32 / v_pk_add_f32 (gfx90a+ packed FP32).
    float sv[DPT], cv[DPT];
    #pragma unroll
    for (int p = 0; p < DPT; p += 2) {
        // A = a-b edge pair, B = b-c edge pair (+eps), C = c-d edge pair
        const v2 axv = mk2(ex[p],   ex[p+1]);
        const v2 ayv = mk2(ey[p],   ey[p+1]);
        const v2 azv = mk2(ez[p],   ez[p+1]);
        const v2 brx = mk2(ex[p+1], ex[p+2]) + EPS_SHIFT;
        const v2 bry = mk2(ey[p+1], ey[p+2]) + EPS_SHIFT;
        const v2 brz = mk2(ez[p+1], ez[p+2]) + EPS_SHIFT;
        const v2 cxv = mk2(ex[p+2], ex[p+3]);
        const v2 cyv = mk2(ey[p+2], ey[p+3]);
        const v2 czv = mk2(ez[p+2], ez[p+3]);

        v2 nrm2 = brx*brx + bry*bry + brz*brz;
        nrm2 = __builtin_elementwise_max(nrm2, (v2)1e-24f);
        v2 inv; inv[0] = rsqrtf(nrm2[0]); inv[1] = rsqrtf(nrm2[1]);
        const v2 ux = brx * inv, uy = bry * inv, uz = brz * inv;

        // n1 = cross(A, u)
        const v2 n1x = ayv*uz - azv*uy;
        const v2 n1y = azv*ux - axv*uz;
        const v2 n1z = axv*uy - ayv*ux;
        // n2 = cross(u, C)
        const v2 n2x = uy*czv - uz*cyv;
        const v2 n2y = uz*cxv - ux*czv;
        const v2 n2z = ux*cyv - uy*cxv;

        const v2 xc = n1x*n2x + n1y*n2y + n1z*n2z;
        // m = cross(n1, u)
        const v2 mx = n1y*uz - n1z*uy;
        const v2 my = n1z*ux - n1x*uz;
        const v2 mz = n1x*uy - n1y*ux;
        const v2 yc = mx*n2x + my*n2y + mz*n2z;

        const v2 xz = xc + EPS_SHIFT;
        const v2 r2 = yc*yc + xz*xz;
        v2 rr = __builtin_elementwise_max(r2, (v2)1e-30f);
        v2 rinv; rinv[0] = rsqrtf(rr[0]); rinv[1] = rsqrtf(rr[1]);
        const v2 sres = yc * rinv;
        const v2 cres = xz * rinv;

        #pragma unroll
        for (int i = 0; i < 2; ++i) {
            sv[p+i] = (r2[i] > 0.0f) ? sres[i] : 0.0f;
            cv[p+i] = (r2[i] > 0.0f) ? cres[i] : 1.0f;
        }
    }

    // ---- direct global stores, no barriers, no LDS transpose ----
    const size_t obase = (size_t)b * ANG_PER_ROW;
    float* so = out + obase + i0;
    float* co = out + obase + NDIH + i0;
    const int j0    = 4 * t;
    const int valid = NDIH - i0;                 // >=1024 normally, 1021 last chunk
    if (j0 + 3 < valid) {
        *(float2*)(so + j0)     = make_float2(sv[0], sv[1]);
        *(float2*)(so + j0 + 2) = make_float2(sv[2], sv[3]);
        co[j0+0] = cv[0]; co[j0+1] = cv[1]; co[j0+2] = cv[2]; co[j0+3] = cv[3];
    } else {
        #pragma unroll
        for (int k = 0; k < 4; ++k)
            if (j0 + k < valid) { so[j0+k] = sv[k]; co[j0+k] = cv[k]; }
    }
}

extern "C" void kernel_launch(void* const* d_in, const int* in_sizes, int n_in,
                              void* d_out, int out_size, void* d_ws, size_t ws_size,
                              hipStream_t stream) {
    const float* in = (const float*)d_in[0];
    float* out = (float*)d_out;
    dih_kernel<<<dim3(ROWS * NCHUNK), dim3(THREADS), 0, stream>>>(in, out);
}